// Round 7
// baseline (435.718 us; speedup 1.0000x reference)
//
#include <hip/hip_runtime.h>
#include <hip/hip_bf16.h>
#include <math.h>

#define NBATCH 2048
#define NAG 32
#define HIDD 256
#define INDIM 256
#define PIN 320
#define NACTN 20
#define NEGV -1e10f
#define MT 64                      // rows per block (= 2 batches)
#define NROWS (NBATCH*NAG)         // 65536

typedef __attribute__((ext_vector_type(8))) __bf16 bf16x8;
typedef __attribute__((ext_vector_type(4))) float f32x4;

// ---- bf16 weight cache layout in d_ws (element offsets) ----
#define WO_W1   0
#define WO_WIH  65536
#define WO_WHH  262144
#define WO_WQ   458752
#define WO_WK   475136
#define WO_WV   491520
#define WO_WG   507904
#define WO_WP1  508928
#define WO_WP2  590848

__device__ __forceinline__ unsigned short f2bf(float f) {
    union { float f; unsigned int i; } x; x.f = f;
    unsigned int r = x.i + 0x7fffu + ((x.i >> 16) & 1u);
    return (unsigned short)(r >> 16);
}
__device__ __forceinline__ float bf2f(unsigned short u) {
    union { unsigned int i; float f; } x; x.i = ((unsigned int)u) << 16; return x.f;
}
__device__ __forceinline__ float frcp(float x) { return __builtin_amdgcn_rcpf(x); }
__device__ __forceinline__ float sigm(float x) { return frcp(1.0f + __expf(-x)); }
__device__ __forceinline__ float tanh_fast(float x) {
    float e = __expf(2.0f * x);
    return 1.0f - 2.0f * frcp(e + 1.0f);
}
// unpack 8 bf16 (uint4) -> 8 fp32, 1 VALU op each
__device__ __forceinline__ void unpack8(uint4 v, float* f) {
    union UF { unsigned int u; float x; } t;
    t.u = v.x << 16;          f[0] = t.x;
    t.u = v.x & 0xffff0000u;  f[1] = t.x;
    t.u = v.y << 16;          f[2] = t.x;
    t.u = v.y & 0xffff0000u;  f[3] = t.x;
    t.u = v.z << 16;          f[4] = t.x;
    t.u = v.z & 0xffff0000u;  f[5] = t.x;
    t.u = v.w << 16;          f[6] = t.x;
    t.u = v.w & 0xffff0000u;  f[7] = t.x;
}

// swizzled addressing for 256-col bf16 buffers
__device__ __forceinline__ int swz(int row, int col) {
    return row*256 + ((((col >> 3)) ^ (row & 7)) << 3) + (col & 7);
}
__device__ __forceinline__ int swzf(int row, int frag) {   // 8-elem fragment base
    return row*256 + ((frag ^ (row & 7)) << 3);
}
// swizzled addressing for 64-col bf16 msg buffer
__device__ __forceinline__ int swzf64(int row, int frag) {
    return row*64 + ((frag ^ (row & 7)) << 3);
}

__device__ __forceinline__ bf16x8 ldfrag(const unsigned short* p) {
    return *(const bf16x8*)(const void*)p;
}
union ZU { uint4 u; bf16x8 v; };
__device__ __forceinline__ bf16x8 zfrag() {
    ZU x; x.u = make_uint4(0u, 0u, 0u, 0u); return x.v;
}
#define MFMA(a,b,c) __builtin_amdgcn_mfma_f32_16x16x32_bf16(a,b,c,0,0,0)

// ---- pre-pass: convert fp32 weight matrices to bf16 in d_ws ----
__global__ void __launch_bounds__(256)
convert_weights(const float* __restrict__ W1,  const float* __restrict__ Wih,
                const float* __restrict__ Whh, const float* __restrict__ Wq,
                const float* __restrict__ Wk,  const float* __restrict__ Wv,
                const float* __restrict__ Wg,  const float* __restrict__ Wp1,
                const float* __restrict__ Wp2, unsigned short* __restrict__ dst)
{
    int b = (int)blockIdx.x;
    const float* src; int base;
    if      (b <  64) { src = W1;  base = WO_W1;              }
    else if (b < 256) { src = Wih; base = WO_WIH; b -=  64;   }
    else if (b < 448) { src = Whh; base = WO_WHH; b -= 256;   }
    else if (b < 464) { src = Wq;  base = WO_WQ;  b -= 448;   }
    else if (b < 480) { src = Wk;  base = WO_WK;  b -= 464;   }
    else if (b < 496) { src = Wv;  base = WO_WV;  b -= 480;   }
    else if (b < 497) { src = Wg;  base = WO_WG;  b -= 496;   }
    else if (b < 577) { src = Wp1; base = WO_WP1; b -= 497;   }
    else              { src = Wp2; base = WO_WP2; b -= 577;   }
    const int idx = b * 1024 + (int)threadIdx.x * 4;
    float4 v = *(const float4*)(const void*)(src + idx);
    ushort4 u;
    u.x = f2bf(v.x); u.y = f2bf(v.y); u.z = f2bf(v.z); u.w = f2bf(v.w);
    *(ushort4*)(void*)(dst + base + idx) = u;
}

// =====================================================================
// Megakernel: one block = 64 rows = 2 batches. Full forward pass.
// LDS lifecycle:  lA: IN -> x -> h       lB: h_old -> q/k/v -> p1x
//                 lM: msg                sG: gate logits
// 72.5 KB LDS -> 2 blocks/CU, (256,2) -> 256-reg budget (P2 ~180 peak).
// h_new carried in registers (bf16-packed) across the P2 barrier:
// no outH re-read (saves 67 MB FETCH vs R6).
// =====================================================================
#define QS 72   // q/k/v LDS row stride: 144 B = 16B-aligned rows for uint4
__global__ void __launch_bounds__(256, 2)
mega(const float* __restrict__ gIn, const float* __restrict__ gH,
     const unsigned short* __restrict__ wsW,
     const float* __restrict__ B1,
     const float* __restrict__ Bih, const float* __restrict__ Bhh,
     const float* __restrict__ Bq,  const float* __restrict__ Bk,
     const float* __restrict__ Bv,  const float* __restrict__ Bg,
     const float* __restrict__ Bp1, const float* __restrict__ Bp2,
     float* __restrict__ outH, float* __restrict__ outL)
{
    __shared__ __align__(16) unsigned short lA[MT*256];   // IN -> x -> h
    __shared__ __align__(16) unsigned short lB[MT*256];   // h_old -> qkv -> p1x
    __shared__ __align__(16) unsigned short lM[MT*64];    // msg (swz64)
    __shared__ __align__(16) unsigned short sG[2*32*4];   // gate logits

    const unsigned short* W1  = wsW + WO_W1;
    const unsigned short* Wih = wsW + WO_WIH;
    const unsigned short* Whh = wsW + WO_WHH;
    const unsigned short* Wq  = wsW + WO_WQ;
    const unsigned short* Wk  = wsW + WO_WK;
    const unsigned short* Wv  = wsW + WO_WV;
    const unsigned short* Wg  = wsW + WO_WG;
    const unsigned short* Wp1 = wsW + WO_WP1;
    const unsigned short* Wp2 = wsW + WO_WP2;

    const int tid  = (int)threadIdx.x;
    const int lane = tid & 63;
    const int wv   = tid >> 6;
    const int l15  = lane & 15;
    const int quad = lane >> 4;
    const long rowBase = (long)blockIdx.x * MT;

    // ---- P0: stage IN -> lA, h_old -> lB (fp32 -> bf16, swizzled) ----
    #pragma unroll
    for (int i = 0; i < 16; ++i) {
        const int job  = i*256 + tid;        // 4096 = 2 bufs x 64 rows x 32 frags
        const int frag = job & 31;
        const int row  = (job >> 5) & 63;
        const int buf  = job >> 11;
        const float* src = (buf ? gH : gIn) + (rowBase + row)*256 + frag*8;
        float4 v0 = *(const float4*)(const void*)(src);
        float4 v1 = *(const float4*)(const void*)(src + 4);
        uint4 pk;
        pk.x = ((unsigned int)f2bf(v0.y) << 16) | f2bf(v0.x);
        pk.y = ((unsigned int)f2bf(v0.w) << 16) | f2bf(v0.z);
        pk.z = ((unsigned int)f2bf(v1.y) << 16) | f2bf(v1.x);
        pk.w = ((unsigned int)f2bf(v1.w) << 16) | f2bf(v1.z);
        unsigned short* dst = buf ? lB : lA;
        *(uint4*)(void*)(dst + swzf(row, frag)) = pk;
    }
    __syncthreads();

    // ---- P1: x = relu(IN @ W1^T + b1) -> regs, then overlay onto lA ----
    f32x4 xa[4][4];
    #pragma unroll
    for (int i4 = 0; i4 < 4; ++i4) {
        const int nt = i4*4 + wv;
        const int n  = nt*16 + l15;
        f32x4 a0 = {0.f,0.f,0.f,0.f}, a1 = {0.f,0.f,0.f,0.f};
        f32x4 a2 = {0.f,0.f,0.f,0.f}, a3 = {0.f,0.f,0.f,0.f};
        #pragma unroll
        for (int kt = 0; kt < 8; ++kt) {
            const int frag = kt*4 + quad;
            bf16x8 bw = ldfrag(W1 + n*INDIM + frag*8);
            a0 = MFMA(ldfrag(lA + swzf(     l15, frag)), bw, a0);
            a1 = MFMA(ldfrag(lA + swzf(16 + l15, frag)), bw, a1);
            a2 = MFMA(ldfrag(lA + swzf(32 + l15, frag)), bw, a2);
            a3 = MFMA(ldfrag(lA + swzf(48 + l15, frag)), bw, a3);
        }
        const float b = B1[n];
        #pragma unroll
        for (int r = 0; r < 4; ++r) {
            a0[r] = fmaxf(a0[r] + b, 0.f); a1[r] = fmaxf(a1[r] + b, 0.f);
            a2[r] = fmaxf(a2[r] + b, 0.f); a3[r] = fmaxf(a3[r] + b, 0.f);
        }
        xa[i4][0] = a0; xa[i4][1] = a1; xa[i4][2] = a2; xa[i4][3] = a3;
    }
    __syncthreads();              // all IN reads complete
    #pragma unroll
    for (int i4 = 0; i4 < 4; ++i4) {
        const int nt = i4*4 + wv;
        #pragma unroll
        for (int m = 0; m < 4; ++m) {
            #pragma unroll
            for (int r = 0; r < 4; ++r)
                lA[swz(m*16 + quad*4 + r, nt*16 + l15)] = f2bf(xa[i4][m][r]);
        }
    }
    __syncthreads();

    // ---- P2: GRU -> h_new (fp32 to outH; bf16 packed into hreg) ----
    unsigned int hreg[4][8];      // static-indexed carry of bf16 h pairs
    #pragma unroll
    for (int i = 0; i < 4; ++i) {
        const int jt = i*4 + wv;
        const int n = jt*16 + l15;
        f32x4 ir[4], iz[4], in_[4], hr[4], hz[4], hn[4];
        #pragma unroll
        for (int m = 0; m < 4; ++m) {
            ir[m] = (f32x4){0.f,0.f,0.f,0.f}; iz[m] = (f32x4){0.f,0.f,0.f,0.f};
            in_[m]= (f32x4){0.f,0.f,0.f,0.f}; hr[m] = (f32x4){0.f,0.f,0.f,0.f};
            hz[m] = (f32x4){0.f,0.f,0.f,0.f}; hn[m] = (f32x4){0.f,0.f,0.f,0.f};
        }
        #pragma unroll 2
        for (int kt = 0; kt < 8; ++kt) {
            const int frag = kt*4 + quad;
            const int k0 = frag*8;
            bf16x8 ax[4], ah[4];
            #pragma unroll
            for (int m = 0; m < 4; ++m) {
                ax[m] = ldfrag(lA + swzf(m*16 + l15, frag));
                ah[m] = ldfrag(lB + swzf(m*16 + l15, frag));
            }
            bf16x8 br = ldfrag(Wih + (n      )*HIDD + k0);
            bf16x8 bz = ldfrag(Wih + (n + 256)*HIDD + k0);
            bf16x8 bn = ldfrag(Wih + (n + 512)*HIDD + k0);
            bf16x8 cr = ldfrag(Whh + (n      )*HIDD + k0);
            bf16x8 cz = ldfrag(Whh + (n + 256)*HIDD + k0);
            bf16x8 cn = ldfrag(Whh + (n + 512)*HIDD + k0);
            #pragma unroll
            for (int m = 0; m < 4; ++m) {
                ir[m] = MFMA(ax[m], br, ir[m]);
                iz[m] = MFMA(ax[m], bz, iz[m]);
                in_[m]= MFMA(ax[m], bn, in_[m]);
                hr[m] = MFMA(ah[m], cr, hr[m]);
                hz[m] = MFMA(ah[m], cz, hz[m]);
                hn[m] = MFMA(ah[m], cn, hn[m]);
            }
        }
        const float bir_ = Bih[n], biz_ = Bih[n+256], bin_ = Bih[n+512];
        const float bhr_ = Bhh[n], bhz_ = Bhh[n+256], bhn_ = Bhh[n+512];
        #pragma unroll
        for (int m = 0; m < 4; ++m) {
            float hv4[4];
            #pragma unroll
            for (int r = 0; r < 4; ++r) {
                const int row = m*16 + quad*4 + r;
                const float hprev = bf2f(lB[swz(row, n)]);
                const float rr = sigm(ir[m][r] + bir_ + hr[m][r] + bhr_);
                const float zz = sigm(iz[m][r] + biz_ + hz[m][r] + bhz_);
                const float nn = tanh_fast(in_[m][r] + bin_ + rr*(hn[m][r] + bhn_));
                const float hv = (1.0f - zz)*nn + zz*hprev;
                outH[(rowBase + row)*HIDD + n] = hv;
                hv4[r] = hv;
            }
            hreg[i][m*2+0] = (unsigned int)f2bf(hv4[0])
                           | ((unsigned int)f2bf(hv4[1]) << 16);
            hreg[i][m*2+1] = (unsigned int)f2bf(hv4[2])
                           | ((unsigned int)f2bf(hv4[3]) << 16);
        }
    }
    __syncthreads();              // all lA(x)/lB(h_old) reads complete

    // ---- P3: dump h bf16 from registers -> lA swizzled (no global read) ----
    #pragma unroll
    for (int i = 0; i < 4; ++i) {
        const int jt = i*4 + wv;
        const int n = jt*16 + l15;
        #pragma unroll
        for (int m = 0; m < 4; ++m) {
            #pragma unroll
            for (int rp = 0; rp < 2; ++rp) {
                const unsigned int pk = hreg[i][m*2 + rp];
                const int row = m*16 + quad*4 + rp*2;
                lA[swz(row,     n)] = (unsigned short)(pk & 0xffffu);
                lA[swz(row + 1, n)] = (unsigned short)(pk >> 16);
            }
        }
    }
    __syncthreads();

    // ---- P4: q,k,v -> lB ([b][mat][32][QS]), g -> sG ----
    for (int job = wv; job < 13; job += 4) {
        const unsigned short* W; const float* Bi; int mat, nb;
        if      (job < 4)  { W = Wq; Bi = Bq; mat = 0; nb = job;     }
        else if (job < 8)  { W = Wk; Bi = Bk; mat = 1; nb = job - 4; }
        else if (job < 12) { W = Wv; Bi = Bv; mat = 2; nb = job - 8; }
        else               { W = Wg; Bi = Bg; mat = 3; nb = 0;       }
        const bool isg   = (job == 12);
        const bool valid = !isg || (l15 < 4);
        const int n = nb*16 + l15;
        f32x4 ac[4];
        #pragma unroll
        for (int m = 0; m < 4; ++m) ac[m] = (f32x4){0.f,0.f,0.f,0.f};
        #pragma unroll
        for (int kt = 0; kt < 8; ++kt) {
            const int frag = kt*4 + quad;
            bf16x8 bw = valid ? ldfrag(W + n*HIDD + frag*8) : zfrag();
            #pragma unroll
            for (int m = 0; m < 4; ++m)
                ac[m] = MFMA(ldfrag(lA + swzf(m*16 + l15, frag)), bw, ac[m]);
        }
        if (valid) {
            const float b = Bi[n];
            #pragma unroll
            for (int m = 0; m < 4; ++m) {
                #pragma unroll
                for (int r = 0; r < 4; ++r) {
                    const int row = m*16 + quad*4 + r;     // 0..63
                    const int bb  = row >> 5, qi = row & 31;
                    const float v = ac[m][r] + b;
                    if (isg) sG[bb*128 + qi*4 + l15] = f2bf(v);
                    else     lB[((bb*3 + mat)*32 + qi)*QS + nb*16 + l15] = f2bf(v);
                }
            }
        }
    }
    __syncthreads();

    // ---- P5: sparse attention, 1 thread per (b,h,qi); msg -> lM ----
    {
        const int b  = tid >> 7;
        const int h  = (tid >> 5) & 3;
        const int qi = tid & 31;
        const unsigned short* q_ = lB + (b*3 + 0)*32*QS;
        const unsigned short* k_ = lB + (b*3 + 1)*32*QS;
        const unsigned short* v_ = lB + (b*3 + 2)*32*QS;

        float qv[16];
        unpack8(*(const uint4*)(const void*)(q_ + qi*QS + h*16),     qv);
        unpack8(*(const uint4*)(const void*)(q_ + qi*QS + h*16 + 8), qv + 8);
        float s0[32];
        #pragma unroll
        for (int ki = 0; ki < 32; ++ki) {
            float kb[16];
            unpack8(*(const uint4*)(const void*)(k_ + ki*QS + h*16),     kb);
            unpack8(*(const uint4*)(const void*)(k_ + ki*QS + h*16 + 8), kb + 8);
            float acc = 0.0f;
            #pragma unroll
            for (int c = 0; c < 16; ++c) acc += qv[c] * kb[c];
            acc *= 0.25f;                        // 1/sqrt(16)
            s0[ki] = (ki == qi) ? NEGV : acc;    // diagonal mask
        }
        // top-8, lowest index wins ties (matches lax.top_k)
        unsigned int mask = 0u;
        float m1 = 0.0f;
        for (int t = 0; t < 8; ++t) {
            float best = -3.0e38f; int bidx = 0;
            #pragma unroll
            for (int i = 0; i < 32; ++i) {
                bool better = (((mask >> i) & 1u) == 0u) && (s0[i] > best);
                best = better ? s0[i] : best;
                bidx = better ? i : bidx;
            }
            mask |= (1u << bidx);
            if (t == 0) m1 = best;
        }
        float sum = 0.0f;
        #pragma unroll
        for (int i = 0; i < 32; ++i) {
            const float e = ((mask >> i) & 1u) ? __expf(s0[i] - m1) : 0.0f;
            s0[i] = e;
            sum += e;
        }
        const float inv = frcp(sum);
        const float gate = sigm(bf2f(sG[b*128 + qi*4 + h]));
        float msg[16];
        #pragma unroll
        for (int c = 0; c < 16; ++c) msg[c] = 0.0f;
        #pragma unroll
        for (int ki = 0; ki < 32; ++ki) {
            const float al = s0[ki] * inv;
            float vb[16];
            unpack8(*(const uint4*)(const void*)(v_ + ki*QS + h*16),     vb);
            unpack8(*(const uint4*)(const void*)(v_ + ki*QS + h*16 + 8), vb + 8);
            #pragma unroll
            for (int c = 0; c < 16; ++c) msg[c] += al * vb[c];
        }
        const int mrow = b*32 + qi;
        unsigned int mw[8];
        #pragma unroll
        for (int p = 0; p < 8; ++p)
            mw[p] = (unsigned int)f2bf(msg[2*p] * gate)
                  | ((unsigned int)f2bf(msg[2*p+1] * gate) << 16);
        *(uint4*)(void*)(lM + swzf64(mrow, h*2))     = make_uint4(mw[0], mw[1], mw[2], mw[3]);
        *(uint4*)(void*)(lM + swzf64(mrow, h*2 + 1)) = make_uint4(mw[4], mw[5], mw[6], mw[7]);
    }
    __syncthreads();   // q/k/v reads done; msg complete; lB reusable

    // ---- P6: p1x = relu([h | msg] @ Wp1^T + b) -> lB (bf16 swz) ----
    #pragma unroll
    for (int i4 = 0; i4 < 4; ++i4) {
        const int nt = i4*4 + wv;
        const int n  = nt*16 + l15;
        f32x4 a0 = {0.f,0.f,0.f,0.f}, a1 = {0.f,0.f,0.f,0.f};
        f32x4 a2 = {0.f,0.f,0.f,0.f}, a3 = {0.f,0.f,0.f,0.f};
        #pragma unroll
        for (int kt = 0; kt < 10; ++kt) {
            bf16x8 bw = ldfrag(Wp1 + n*PIN + kt*32 + quad*8);
            bf16x8 f0, f1, f2, f3;
            if (kt < 8) {
                const int frag = kt*4 + quad;
                f0 = ldfrag(lA + swzf(     l15, frag));
                f1 = ldfrag(lA + swzf(16 + l15, frag));
                f2 = ldfrag(lA + swzf(32 + l15, frag));
                f3 = ldfrag(lA + swzf(48 + l15, frag));
            } else {
                const int frag = (kt - 8)*4 + quad;
                f0 = ldfrag(lM + swzf64(     l15, frag));
                f1 = ldfrag(lM + swzf64(16 + l15, frag));
                f2 = ldfrag(lM + swzf64(32 + l15, frag));
                f3 = ldfrag(lM + swzf64(48 + l15, frag));
            }
            a0 = MFMA(f0, bw, a0); a1 = MFMA(f1, bw, a1);
            a2 = MFMA(f2, bw, a2); a3 = MFMA(f3, bw, a3);
        }
        const float b = Bp1[n];
        #pragma unroll
        for (int r = 0; r < 4; ++r) {
            lB[swz(     quad*4 + r, n)] = f2bf(fmaxf(a0[r] + b, 0.f));
            lB[swz(16 + quad*4 + r, n)] = f2bf(fmaxf(a1[r] + b, 0.f));
            lB[swz(32 + quad*4 + r, n)] = f2bf(fmaxf(a2[r] + b, 0.f));
            lB[swz(48 + quad*4 + r, n)] = f2bf(fmaxf(a3[r] + b, 0.f));
        }
    }
    __syncthreads();

    // ---- P7: logits = p1x @ Wp2^T + b ----
    for (int j = wv; j < 8; j += 4) {
        const int ntile = j >> 2, m = j & 3;
        const int n = ntile*16 + l15;
        const bool valid = (n < NACTN);
        f32x4 ac = {0.f,0.f,0.f,0.f};
        #pragma unroll
        for (int kt = 0; kt < 8; ++kt) {
            const int frag = kt*4 + quad;
            bf16x8 bw = valid ? ldfrag(Wp2 + n*HIDD + frag*8) : zfrag();
            ac = MFMA(ldfrag(lB + swzf(m*16 + l15, frag)), bw, ac);
        }
        if (valid) {
            const float b = Bp2[n];
            #pragma unroll
            for (int r = 0; r < 4; ++r)
                outL[(rowBase + m*16 + quad*4 + r)*NACTN + n] = ac[r] + b;
        }
    }
}

extern "C" void kernel_launch(void* const* d_in, const int* in_sizes, int n_in,
                              void* d_out, int out_size, void* d_ws, size_t ws_size,
                              hipStream_t stream) {
    (void)in_sizes; (void)n_in; (void)ws_size; (void)out_size;
    const float* gIn = (const float*)d_in[0];
    const float* gH  = (const float*)d_in[1];
    const float* W1  = (const float*)d_in[2];
    const float* B1  = (const float*)d_in[3];
    const float* Wih = (const float*)d_in[4];
    const float* Whh = (const float*)d_in[5];
    const float* Bih = (const float*)d_in[6];
    const float* Bhh = (const float*)d_in[7];
    const float* Wq  = (const float*)d_in[8];
    const float* Bq  = (const float*)d_in[9];
    const float* Wk  = (const float*)d_in[10];
    const float* Bk  = (const float*)d_in[11];
    const float* Wv  = (const float*)d_in[12];
    const float* Bv  = (const float*)d_in[13];
    const float* Wg  = (const float*)d_in[14];
    const float* Bg  = (const float*)d_in[15];
    const float* Wp1 = (const float*)d_in[16];
    const float* Bp1 = (const float*)d_in[17];
    const float* Wp2 = (const float*)d_in[18];
    const float* Bp2 = (const float*)d_in[19];
    float* outL = (float*)d_out;
    float* outH = outL + (size_t)NBATCH * NAG * NACTN;
    unsigned short* wsW = (unsigned short*)d_ws;

    hipLaunchKernelGGL(convert_weights, dim3(582), dim3(256), 0, stream,
        W1, Wih, Whh, Wq, Wk, Wv, Wg, Wp1, Wp2, wsW);
    hipLaunchKernelGGL(mega, dim3(NROWS/MT), dim3(256), 0, stream,
        gIn, gH, wsW, B1, Bih, Bhh, Bq, Bk, Bv, Bg, Bp1, Bp2, outH, outL);
}

// Round 8
// 383.546 us; speedup vs baseline: 1.1360x; 1.1360x over previous
//
#include <hip/hip_runtime.h>
#include <hip/hip_bf16.h>
#include <math.h>

#define NBATCH 2048
#define NAG 32
#define HIDD 256
#define INDIM 256
#define PIN 320
#define NACTN 20
#define NEGV -1e10f
#define MT 64                      // rows per block (= 2 batches)
#define NROWS (NBATCH*NAG)         // 65536

typedef __attribute__((ext_vector_type(8))) __bf16 bf16x8;
typedef __attribute__((ext_vector_type(4))) float f32x4;

// ---- bf16 weight cache layout in d_ws (element offsets) ----
#define WO_W1   0
#define WO_WIH  65536
#define WO_WHH  262144
#define WO_WQ   458752
#define WO_WK   475136
#define WO_WV   491520
#define WO_WG   507904
#define WO_WP1  508928
#define WO_WP2  590848

__device__ __forceinline__ unsigned short f2bf(float f) {
    union { float f; unsigned int i; } x; x.f = f;
    unsigned int r = x.i + 0x7fffu + ((x.i >> 16) & 1u);
    return (unsigned short)(r >> 16);
}
__device__ __forceinline__ float bf2f(unsigned short u) {
    union { unsigned int i; float f; } x; x.i = ((unsigned int)u) << 16; return x.f;
}
__device__ __forceinline__ float frcp(float x) { return __builtin_amdgcn_rcpf(x); }
__device__ __forceinline__ float sigm(float x) { return frcp(1.0f + __expf(-x)); }
__device__ __forceinline__ float tanh_fast(float x) {
    float e = __expf(2.0f * x);
    return 1.0f - 2.0f * frcp(e + 1.0f);
}
// unpack 8 bf16 (uint4) -> 8 fp32, 1 VALU op each
__device__ __forceinline__ void unpack8(uint4 v, float* f) {
    union UF { unsigned int u; float x; } t;
    t.u = v.x << 16;          f[0] = t.x;
    t.u = v.x & 0xffff0000u;  f[1] = t.x;
    t.u = v.y << 16;          f[2] = t.x;
    t.u = v.y & 0xffff0000u;  f[3] = t.x;
    t.u = v.z << 16;          f[4] = t.x;
    t.u = v.z & 0xffff0000u;  f[5] = t.x;
    t.u = v.w << 16;          f[6] = t.x;
    t.u = v.w & 0xffff0000u;  f[7] = t.x;
}

// swizzled addressing for 256-col bf16 buffers
__device__ __forceinline__ int swz(int row, int col) {
    return row*256 + ((((col >> 3)) ^ (row & 7)) << 3) + (col & 7);
}
__device__ __forceinline__ int swzf(int row, int frag) {   // 8-elem fragment base
    return row*256 + ((frag ^ (row & 7)) << 3);
}
// swizzled addressing for 64-col bf16 msg buffer
__device__ __forceinline__ int swzf64(int row, int frag) {
    return row*64 + ((frag ^ (row & 7)) << 3);
}

__device__ __forceinline__ bf16x8 ldfrag(const unsigned short* p) {
    return *(const bf16x8*)(const void*)p;
}
union ZU { uint4 u; bf16x8 v; };
__device__ __forceinline__ bf16x8 zfrag() {
    ZU x; x.u = make_uint4(0u, 0u, 0u, 0u); return x.v;
}
#define MFMA(a,b,c) __builtin_amdgcn_mfma_f32_16x16x32_bf16(a,b,c,0,0,0)

// ---- pre-pass: convert fp32 weight matrices to bf16 in d_ws ----
__global__ void __launch_bounds__(256)
convert_weights(const float* __restrict__ W1,  const float* __restrict__ Wih,
                const float* __restrict__ Whh, const float* __restrict__ Wq,
                const float* __restrict__ Wk,  const float* __restrict__ Wv,
                const float* __restrict__ Wg,  const float* __restrict__ Wp1,
                const float* __restrict__ Wp2, unsigned short* __restrict__ dst)
{
    int b = (int)blockIdx.x;
    const float* src; int base;
    if      (b <  64) { src = W1;  base = WO_W1;              }
    else if (b < 256) { src = Wih; base = WO_WIH; b -=  64;   }
    else if (b < 448) { src = Whh; base = WO_WHH; b -= 256;   }
    else if (b < 464) { src = Wq;  base = WO_WQ;  b -= 448;   }
    else if (b < 480) { src = Wk;  base = WO_WK;  b -= 464;   }
    else if (b < 496) { src = Wv;  base = WO_WV;  b -= 480;   }
    else if (b < 497) { src = Wg;  base = WO_WG;  b -= 496;   }
    else if (b < 577) { src = Wp1; base = WO_WP1; b -= 497;   }
    else              { src = Wp2; base = WO_WP2; b -= 577;   }
    const int idx = b * 1024 + (int)threadIdx.x * 4;
    float4 v = *(const float4*)(const void*)(src + idx);
    ushort4 u;
    u.x = f2bf(v.x); u.y = f2bf(v.y); u.z = f2bf(v.z); u.w = f2bf(v.w);
    *(ushort4*)(void*)(dst + base + idx) = u;
}

// =====================================================================
// Megakernel: one block = 64 rows = 2 batches. Full forward pass.
// LDS lifecycle:  lA: IN -> x -> h       lB: h_old -> q/k/v -> p1x
//                 lM: msg                sG: gate logits
// 72.5 KB LDS -> 2 blocks/CU, (256,2) -> compiler pins 128 VGPR.
// RULE (R3/R4/R7 post-mortems): no new register state may live across
// a barrier — cross-phase state goes through LDS or L2 (outH restage).
// =====================================================================
#define QS 72   // q/k/v LDS row stride: 144 B = 16B-aligned rows for uint4
__global__ void __launch_bounds__(256, 2)
mega(const float* __restrict__ gIn, const float* __restrict__ gH,
     const unsigned short* __restrict__ wsW,
     const float* __restrict__ B1,
     const float* __restrict__ Bih, const float* __restrict__ Bhh,
     const float* __restrict__ Bq,  const float* __restrict__ Bk,
     const float* __restrict__ Bv,  const float* __restrict__ Bg,
     const float* __restrict__ Bp1, const float* __restrict__ Bp2,
     float* __restrict__ outH, float* __restrict__ outL)
{
    __shared__ __align__(16) unsigned short lA[MT*256];   // IN -> x -> h
    __shared__ __align__(16) unsigned short lB[MT*256];   // h_old -> qkv -> p1x
    __shared__ __align__(16) unsigned short lM[MT*64];    // msg (swz64)
    __shared__ __align__(16) unsigned short sG[2*32*4];   // gate logits

    const unsigned short* W1  = wsW + WO_W1;
    const unsigned short* Wih = wsW + WO_WIH;
    const unsigned short* Whh = wsW + WO_WHH;
    const unsigned short* Wq  = wsW + WO_WQ;
    const unsigned short* Wk  = wsW + WO_WK;
    const unsigned short* Wv  = wsW + WO_WV;
    const unsigned short* Wg  = wsW + WO_WG;
    const unsigned short* Wp1 = wsW + WO_WP1;
    const unsigned short* Wp2 = wsW + WO_WP2;

    const int tid  = (int)threadIdx.x;
    const int lane = tid & 63;
    const int wv   = tid >> 6;
    const int l15  = lane & 15;
    const int quad = lane >> 4;
    const long rowBase = (long)blockIdx.x * MT;

    // ---- P0: stage IN -> lA, h_old -> lB (fp32 -> bf16, swizzled) ----
    #pragma unroll
    for (int i = 0; i < 16; ++i) {
        const int job  = i*256 + tid;        // 4096 = 2 bufs x 64 rows x 32 frags
        const int frag = job & 31;
        const int row  = (job >> 5) & 63;
        const int buf  = job >> 11;
        const float* src = (buf ? gH : gIn) + (rowBase + row)*256 + frag*8;
        float4 v0 = *(const float4*)(const void*)(src);
        float4 v1 = *(const float4*)(const void*)(src + 4);
        uint4 pk;
        pk.x = ((unsigned int)f2bf(v0.y) << 16) | f2bf(v0.x);
        pk.y = ((unsigned int)f2bf(v0.w) << 16) | f2bf(v0.z);
        pk.z = ((unsigned int)f2bf(v1.y) << 16) | f2bf(v1.x);
        pk.w = ((unsigned int)f2bf(v1.w) << 16) | f2bf(v1.z);
        unsigned short* dst = buf ? lB : lA;
        *(uint4*)(void*)(dst + swzf(row, frag)) = pk;
    }
    __syncthreads();

    // ---- P1: x = relu(IN @ W1^T + b1) -> regs, then overlay onto lA ----
    f32x4 xa[4][4];
    #pragma unroll
    for (int i4 = 0; i4 < 4; ++i4) {
        const int nt = i4*4 + wv;
        const int n  = nt*16 + l15;
        f32x4 a0 = {0.f,0.f,0.f,0.f}, a1 = {0.f,0.f,0.f,0.f};
        f32x4 a2 = {0.f,0.f,0.f,0.f}, a3 = {0.f,0.f,0.f,0.f};
        #pragma unroll
        for (int kt = 0; kt < 8; ++kt) {
            const int frag = kt*4 + quad;
            bf16x8 bw = ldfrag(W1 + n*INDIM + frag*8);
            a0 = MFMA(ldfrag(lA + swzf(     l15, frag)), bw, a0);
            a1 = MFMA(ldfrag(lA + swzf(16 + l15, frag)), bw, a1);
            a2 = MFMA(ldfrag(lA + swzf(32 + l15, frag)), bw, a2);
            a3 = MFMA(ldfrag(lA + swzf(48 + l15, frag)), bw, a3);
        }
        const float b = B1[n];
        #pragma unroll
        for (int r = 0; r < 4; ++r) {
            a0[r] = fmaxf(a0[r] + b, 0.f); a1[r] = fmaxf(a1[r] + b, 0.f);
            a2[r] = fmaxf(a2[r] + b, 0.f); a3[r] = fmaxf(a3[r] + b, 0.f);
        }
        xa[i4][0] = a0; xa[i4][1] = a1; xa[i4][2] = a2; xa[i4][3] = a3;
    }
    __syncthreads();              // all IN reads complete
    #pragma unroll
    for (int i4 = 0; i4 < 4; ++i4) {
        const int nt = i4*4 + wv;
        #pragma unroll
        for (int m = 0; m < 4; ++m) {
            #pragma unroll
            for (int r = 0; r < 4; ++r)
                lA[swz(m*16 + quad*4 + r, nt*16 + l15)] = f2bf(xa[i4][m][r]);
        }
    }
    __syncthreads();

    // ---- P2: GRU -> h_new (fp32 to outH) ----
    for (int jt = wv; jt < 16; jt += 4) {
        const int n = jt*16 + l15;
        f32x4 ir[4], iz[4], in_[4], hr[4], hz[4], hn[4];
        #pragma unroll
        for (int m = 0; m < 4; ++m) {
            ir[m] = (f32x4){0.f,0.f,0.f,0.f}; iz[m] = (f32x4){0.f,0.f,0.f,0.f};
            in_[m]= (f32x4){0.f,0.f,0.f,0.f}; hr[m] = (f32x4){0.f,0.f,0.f,0.f};
            hz[m] = (f32x4){0.f,0.f,0.f,0.f}; hn[m] = (f32x4){0.f,0.f,0.f,0.f};
        }
        #pragma unroll 2
        for (int kt = 0; kt < 8; ++kt) {
            const int frag = kt*4 + quad;
            const int k0 = frag*8;
            bf16x8 ax[4], ah[4];
            #pragma unroll
            for (int m = 0; m < 4; ++m) {
                ax[m] = ldfrag(lA + swzf(m*16 + l15, frag));
                ah[m] = ldfrag(lB + swzf(m*16 + l15, frag));
            }
            bf16x8 br = ldfrag(Wih + (n      )*HIDD + k0);
            bf16x8 bz = ldfrag(Wih + (n + 256)*HIDD + k0);
            bf16x8 bn = ldfrag(Wih + (n + 512)*HIDD + k0);
            bf16x8 cr = ldfrag(Whh + (n      )*HIDD + k0);
            bf16x8 cz = ldfrag(Whh + (n + 256)*HIDD + k0);
            bf16x8 cn = ldfrag(Whh + (n + 512)*HIDD + k0);
            #pragma unroll
            for (int m = 0; m < 4; ++m) {
                ir[m] = MFMA(ax[m], br, ir[m]);
                iz[m] = MFMA(ax[m], bz, iz[m]);
                in_[m]= MFMA(ax[m], bn, in_[m]);
                hr[m] = MFMA(ah[m], cr, hr[m]);
                hz[m] = MFMA(ah[m], cz, hz[m]);
                hn[m] = MFMA(ah[m], cn, hn[m]);
            }
        }
        const float bir_ = Bih[n], biz_ = Bih[n+256], bin_ = Bih[n+512];
        const float bhr_ = Bhh[n], bhz_ = Bhh[n+256], bhn_ = Bhh[n+512];
        #pragma unroll
        for (int m = 0; m < 4; ++m) {
            #pragma unroll
            for (int r = 0; r < 4; ++r) {
                const int row = m*16 + quad*4 + r;
                const float hprev = bf2f(lB[swz(row, n)]);
                const float rr = sigm(ir[m][r] + bir_ + hr[m][r] + bhr_);
                const float zz = sigm(iz[m][r] + biz_ + hz[m][r] + bhz_);
                const float nn = tanh_fast(in_[m][r] + bin_ + rr*(hn[m][r] + bhn_));
                outH[(rowBase + row)*HIDD + n] = (1.0f - zz)*nn + zz*hprev;
            }
        }
    }
    __syncthreads();              // all lA(x)/lB(h_old) reads complete

    // ---- P3: restage h_new (fp32, same-XCD L2-hot) -> lA as bf16 ----
    #pragma unroll
    for (int i = 0; i < 8; ++i) {
        const int job  = i*256 + tid;
        const int frag = job & 31;
        const int row  = job >> 5;
        const float* src = outH + (rowBase + row)*256 + frag*8;
        float4 v0 = *(const float4*)(const void*)(src);
        float4 v1 = *(const float4*)(const void*)(src + 4);
        uint4 pk;
        pk.x = ((unsigned int)f2bf(v0.y) << 16) | f2bf(v0.x);
        pk.y = ((unsigned int)f2bf(v0.w) << 16) | f2bf(v0.z);
        pk.z = ((unsigned int)f2bf(v1.y) << 16) | f2bf(v1.x);
        pk.w = ((unsigned int)f2bf(v1.w) << 16) | f2bf(v1.z);
        *(uint4*)(void*)(lA + swzf(row, frag)) = pk;
    }
    __syncthreads();

    // ---- P4: q,k,v -> lB ([b][mat][32][QS]), g -> sG ----
    for (int job = wv; job < 13; job += 4) {
        const unsigned short* W; const float* Bi; int mat, nb;
        if      (job < 4)  { W = Wq; Bi = Bq; mat = 0; nb = job;     }
        else if (job < 8)  { W = Wk; Bi = Bk; mat = 1; nb = job - 4; }
        else if (job < 12) { W = Wv; Bi = Bv; mat = 2; nb = job - 8; }
        else               { W = Wg; Bi = Bg; mat = 3; nb = 0;       }
        const bool isg   = (job == 12);
        const bool valid = !isg || (l15 < 4);
        const int n = nb*16 + l15;
        f32x4 ac[4];
        #pragma unroll
        for (int m = 0; m < 4; ++m) ac[m] = (f32x4){0.f,0.f,0.f,0.f};
        #pragma unroll
        for (int kt = 0; kt < 8; ++kt) {
            const int frag = kt*4 + quad;
            bf16x8 bw = valid ? ldfrag(W + n*HIDD + frag*8) : zfrag();
            #pragma unroll
            for (int m = 0; m < 4; ++m)
                ac[m] = MFMA(ldfrag(lA + swzf(m*16 + l15, frag)), bw, ac[m]);
        }
        if (valid) {
            const float b = Bi[n];
            #pragma unroll
            for (int m = 0; m < 4; ++m) {
                #pragma unroll
                for (int r = 0; r < 4; ++r) {
                    const int row = m*16 + quad*4 + r;     // 0..63
                    const int bb  = row >> 5, qi = row & 31;
                    const float v = ac[m][r] + b;
                    if (isg) sG[bb*128 + qi*4 + l15] = f2bf(v);
                    else     lB[((bb*3 + mat)*32 + qi)*QS + nb*16 + l15] = f2bf(v);
                }
            }
        }
    }
    __syncthreads();

    // ---- P5: sparse attention, 1 thread per (b,h,qi); msg -> lM ----
    {
        const int b  = tid >> 7;
        const int h  = (tid >> 5) & 3;
        const int qi = tid & 31;
        const unsigned short* q_ = lB + (b*3 + 0)*32*QS;
        const unsigned short* k_ = lB + (b*3 + 1)*32*QS;
        const unsigned short* v_ = lB + (b*3 + 2)*32*QS;

        float qv[16];
        unpack8(*(const uint4*)(const void*)(q_ + qi*QS + h*16),     qv);
        unpack8(*(const uint4*)(const void*)(q_ + qi*QS + h*16 + 8), qv + 8);
        float s0[32];
        #pragma unroll
        for (int ki = 0; ki < 32; ++ki) {
            float kb[16];
            unpack8(*(const uint4*)(const void*)(k_ + ki*QS + h*16),     kb);
            unpack8(*(const uint4*)(const void*)(k_ + ki*QS + h*16 + 8), kb + 8);
            float acc = 0.0f;
            #pragma unroll
            for (int c = 0; c < 16; ++c) acc += qv[c] * kb[c];
            acc *= 0.25f;                        // 1/sqrt(16)
            s0[ki] = (ki == qi) ? NEGV : acc;    // diagonal mask
        }
        // top-8, lowest index wins ties (matches lax.top_k)
        unsigned int mask = 0u;
        float m1 = 0.0f;
        for (int t = 0; t < 8; ++t) {
            float best = -3.0e38f; int bidx = 0;
            #pragma unroll
            for (int i = 0; i < 32; ++i) {
                bool better = (((mask >> i) & 1u) == 0u) && (s0[i] > best);
                best = better ? s0[i] : best;
                bidx = better ? i : bidx;
            }
            mask |= (1u << bidx);
            if (t == 0) m1 = best;
        }
        float sum = 0.0f;
        #pragma unroll
        for (int i = 0; i < 32; ++i) {
            const float e = ((mask >> i) & 1u) ? __expf(s0[i] - m1) : 0.0f;
            s0[i] = e;
            sum += e;
        }
        const float inv = frcp(sum);
        const float gate = sigm(bf2f(sG[b*128 + qi*4 + h]));
        float msg[16];
        #pragma unroll
        for (int c = 0; c < 16; ++c) msg[c] = 0.0f;
        #pragma unroll
        for (int ki = 0; ki < 32; ++ki) {
            const float al = s0[ki] * inv;
            float vb[16];
            unpack8(*(const uint4*)(const void*)(v_ + ki*QS + h*16),     vb);
            unpack8(*(const uint4*)(const void*)(v_ + ki*QS + h*16 + 8), vb + 8);
            #pragma unroll
            for (int c = 0; c < 16; ++c) msg[c] += al * vb[c];
        }
        const int mrow = b*32 + qi;
        unsigned int mw[8];
        #pragma unroll
        for (int p = 0; p < 8; ++p)
            mw[p] = (unsigned int)f2bf(msg[2*p] * gate)
                  | ((unsigned int)f2bf(msg[2*p+1] * gate) << 16);
        *(uint4*)(void*)(lM + swzf64(mrow, h*2))     = make_uint4(mw[0], mw[1], mw[2], mw[3]);
        *(uint4*)(void*)(lM + swzf64(mrow, h*2 + 1)) = make_uint4(mw[4], mw[5], mw[6], mw[7]);
    }
    __syncthreads();   // q/k/v reads done; msg complete; lB reusable

    // ---- P6: p1x = relu([h | msg] @ Wp1^T + b) -> lB (bf16 swz) ----
    #pragma unroll
    for (int i4 = 0; i4 < 4; ++i4) {
        const int nt = i4*4 + wv;
        const int n  = nt*16 + l15;
        f32x4 a0 = {0.f,0.f,0.f,0.f}, a1 = {0.f,0.f,0.f,0.f};
        f32x4 a2 = {0.f,0.f,0.f,0.f}, a3 = {0.f,0.f,0.f,0.f};
        #pragma unroll
        for (int kt = 0; kt < 10; ++kt) {
            bf16x8 bw = ldfrag(Wp1 + n*PIN + kt*32 + quad*8);
            bf16x8 f0, f1, f2, f3;
            if (kt < 8) {
                const int frag = kt*4 + quad;
                f0 = ldfrag(lA + swzf(     l15, frag));
                f1 = ldfrag(lA + swzf(16 + l15, frag));
                f2 = ldfrag(lA + swzf(32 + l15, frag));
                f3 = ldfrag(lA + swzf(48 + l15, frag));
            } else {
                const int frag = (kt - 8)*4 + quad;
                f0 = ldfrag(lM + swzf64(     l15, frag));
                f1 = ldfrag(lM + swzf64(16 + l15, frag));
                f2 = ldfrag(lM + swzf64(32 + l15, frag));
                f3 = ldfrag(lM + swzf64(48 + l15, frag));
            }
            a0 = MFMA(f0, bw, a0); a1 = MFMA(f1, bw, a1);
            a2 = MFMA(f2, bw, a2); a3 = MFMA(f3, bw, a3);
        }
        const float b = Bp1[n];
        #pragma unroll
        for (int r = 0; r < 4; ++r) {
            lB[swz(     quad*4 + r, n)] = f2bf(fmaxf(a0[r] + b, 0.f));
            lB[swz(16 + quad*4 + r, n)] = f2bf(fmaxf(a1[r] + b, 0.f));
            lB[swz(32 + quad*4 + r, n)] = f2bf(fmaxf(a2[r] + b, 0.f));
            lB[swz(48 + quad*4 + r, n)] = f2bf(fmaxf(a3[r] + b, 0.f));
        }
    }
    __syncthreads();

    // ---- P7: logits = p1x @ Wp2^T + b ----
    for (int j = wv; j < 8; j += 4) {
        const int ntile = j >> 2, m = j & 3;
        const int n = ntile*16 + l15;
        const bool valid = (n < NACTN);
        f32x4 ac = {0.f,0.f,0.f,0.f};
        #pragma unroll
        for (int kt = 0; kt < 8; ++kt) {
            const int frag = kt*4 + quad;
            bf16x8 bw = valid ? ldfrag(Wp2 + n*HIDD + frag*8) : zfrag();
            ac = MFMA(ldfrag(lB + swzf(m*16 + l15, frag)), bw, ac);
        }
        if (valid) {
            const float b = Bp2[n];
            #pragma unroll
            for (int r = 0; r < 4; ++r)
                outL[(rowBase + m*16 + quad*4 + r)*NACTN + n] = ac[r] + b;
        }
    }
}

extern "C" void kernel_launch(void* const* d_in, const int* in_sizes, int n_in,
                              void* d_out, int out_size, void* d_ws, size_t ws_size,
                              hipStream_t stream) {
    (void)in_sizes; (void)n_in; (void)ws_size; (void)out_size;
    const float* gIn = (const float*)d_in[0];
    const float* gH  = (const float*)d_in[1];
    const float* W1  = (const float*)d_in[2];
    const float* B1  = (const float*)d_in[3];
    const float* Wih = (const float*)d_in[4];
    const float* Whh = (const float*)d_in[5];
    const float* Bih = (const float*)d_in[6];
    const float* Bhh = (const float*)d_in[7];
    const float* Wq  = (const float*)d_in[8];
    const float* Bq  = (const float*)d_in[9];
    const float* Wk  = (const float*)d_in[10];
    const float* Bk  = (const float*)d_in[11];
    const float* Wv  = (const float*)d_in[12];
    const float* Bv  = (const float*)d_in[13];
    const float* Wg  = (const float*)d_in[14];
    const float* Bg  = (const float*)d_in[15];
    const float* Wp1 = (const float*)d_in[16];
    const float* Bp1 = (const float*)d_in[17];
    const float* Wp2 = (const float*)d_in[18];
    const float* Bp2 = (const float*)d_in[19];
    float* outL = (float*)d_out;
    float* outH = outL + (size_t)NBATCH * NAG * NACTN;
    unsigned short* wsW = (unsigned short*)d_ws;

    hipLaunchKernelGGL(convert_weights, dim3(582), dim3(256), 0, stream,
        W1, Wih, Whh, Wq, Wk, Wv, Wg, Wp1, Wp2, wsW);
    hipLaunchKernelGGL(mega, dim3(NROWS/MT), dim3(256), 0, stream,
        gIn, gH, wsW, B1, Bih, Bhh, Bq, Bk, Bv, Bg, Bp1, Bp2, outH, outL);
}